// Round 3
// baseline (379.184 us; speedup 1.0000x reference)
//
#include <hip/hip_runtime.h>
#include <hip/hip_bf16.h>

#define MTOT 4096   // B*S
#define DD   1024
#define D2   2048
#define SS   2048
#define BB   2
#define NC2  64
#define CL2  (SS/NC2)   // 32

typedef __attribute__((ext_vector_type(8))) short bf16x8;
typedef __attribute__((ext_vector_type(4))) float f32x4;

__device__ __forceinline__ float geluf(float v){
    return 0.5f*v*(1.0f+erff(v*0.70710678118654752f));
}
__device__ __forceinline__ float sigmf(float v){
    return 1.0f/(1.0f+expf(-v));
}
__device__ __forceinline__ ushort f2bf(float f){
    unsigned u = __float_as_uint(f);
    unsigned r = (u + 0x7FFF + ((u>>16)&1)) >> 16;
    return (ushort)r;
}

// ---------------- bf16 MFMA GEMM core (m97 structure) ----------------
// A: bf16 [M][K] row-major.  Bt: bf16 [N][K].  128x128 tile, 4 waves,
// each wave 64x64 = 4x4 fragments of 16x16x32 MFMA. BK=32.
__device__ __forceinline__ void mgemm_core(
    const ushort* __restrict__ A, const ushort* __restrict__ Bt, int K,
    int m0, int n0, ushort* As, ushort* Bs, f32x4 (&acc)[4][4])
{
    int tid  = threadIdx.x;
    int lane = tid & 63, wave = tid >> 6;
    int wr = wave >> 1, wc = wave & 1;
    int lrow = lane & 15, lk8 = (lane >> 4) << 3;
    for (int k0 = 0; k0 < K; k0 += 32) {
        __syncthreads();
        #pragma unroll
        for (int i = 0; i < 2; i++) {
            int e = (i*256 + tid) * 8;
            int r = e >> 5, c = e & 31;
            __builtin_amdgcn_global_load_lds(
                (const __attribute__((address_space(1))) void*)(A + (size_t)(m0 + r)*K + k0 + c),
                (__attribute__((address_space(3))) void*)(As + e), 16, 0, 0);
            __builtin_amdgcn_global_load_lds(
                (const __attribute__((address_space(1))) void*)(Bt + (size_t)(n0 + r)*K + k0 + c),
                (__attribute__((address_space(3))) void*)(Bs + e), 16, 0, 0);
        }
        __syncthreads();
        bf16x8 af[4], bfr[4];
        #pragma unroll
        for (int i = 0; i < 4; i++) {
            af[i]  = *(const bf16x8*)(As + (wr*64 + i*16 + lrow)*32 + lk8);
            bfr[i] = *(const bf16x8*)(Bs + (wc*64 + i*16 + lrow)*32 + lk8);
        }
        #pragma unroll
        for (int i = 0; i < 4; i++)
            #pragma unroll
            for (int j = 0; j < 4; j++)
                acc[i][j] = __builtin_amdgcn_mfma_f32_16x16x32_bf16(af[i], bfr[j], acc[i][j], 0, 0, 0);
    }
}

// Fused GEMM A: xb @ [w_pt1 | w_wg | w_mag | w_q1 | w_mix], N=7168, K=1024.
__global__ __launch_bounds__(256) void mgemmA_k(
    const ushort* __restrict__ xb, const ushort* __restrict__ Wt,
    const float* __restrict__ b_pt1, const float* __restrict__ b_wg,
    const float* __restrict__ b_mag, const float* __restrict__ b_q1,
    const float* __restrict__ b_mix, const float* __restrict__ gtemp,
    ushort* __restrict__ H1b, float* __restrict__ wgf, float* __restrict__ magf,
    ushort* __restrict__ Hqb, float* __restrict__ mixb)
{
    __shared__ ushort As[4096], Bs[4096];
    int m0 = blockIdx.y*128, n0 = blockIdx.x*128;
    f32x4 acc[4][4] = {};
    mgemm_core(xb, Wt, 1024, m0, n0, As, Bs, acc);
    int lane = threadIdx.x & 63, wave = threadIdx.x >> 6;
    int wr = wave >> 1, wc = wave & 1;
    int rng = n0 >> 10;           // 0,1:pt1  2:wg  3:mag  4:q1  5,6:mix
    float gt = gtemp[0];
    #pragma unroll
    for (int i = 0; i < 4; i++) {
        int mb = m0 + wr*64 + i*16 + (lane>>4)*4;
        #pragma unroll
        for (int j = 0; j < 4; j++) {
            int n = n0 + wc*64 + j*16 + (lane&15);
            #pragma unroll
            for (int r = 0; r < 4; r++) {
                int m = mb + r;
                float v = acc[i][j][r];
                if (rng < 2) {
                    H1b[(size_t)m*D2 + n] = f2bf(geluf(v + b_pt1[n]));
                } else if (rng == 2) {
                    wgf[(size_t)m*DD + n-2048] = sigmf((v + b_wg[n-2048])*gt);
                } else if (rng == 3) {
                    magf[(size_t)m*DD + n-3072] = sigmf(v + b_mag[n-3072])*5.0f;
                } else if (rng == 4) {
                    Hqb[(size_t)m*DD + n-4096] = f2bf(geluf(v + b_q1[n-4096]));
                } else {
                    mixb[(size_t)m*D2 + n-5120] = sigmf(v + b_mix[n-5120]);
                }
            }
        }
    }
}

// z=0: pd = (H1 @ w_pt2 + b_pt2) * |iscale|   (K=2048)
// z=1: qadj = Hq @ w_q2 + b_q2                (K=1024)
__global__ __launch_bounds__(256) void mgemmBC_k(
    const ushort* __restrict__ H1b, const ushort* __restrict__ wt_pt2,
    const ushort* __restrict__ Hqb, const ushort* __restrict__ wt_q2,
    const float* __restrict__ b_pt2, const float* __restrict__ b_q2,
    const float* __restrict__ iscale,
    float* __restrict__ pd, float* __restrict__ qadj)
{
    int z = blockIdx.z;
    const ushort* A  = z ? Hqb   : H1b;
    const ushort* Bt = z ? wt_q2 : wt_pt2;
    const float* bias = z ? b_q2 : b_pt2;
    int K = z ? 1024 : 2048;
    float* outp = z ? qadj : pd;
    __shared__ ushort As[4096], Bs[4096];
    int m0 = blockIdx.y*128, n0 = blockIdx.x*128;
    f32x4 acc[4][4] = {};
    mgemm_core(A, Bt, K, m0, n0, As, Bs, acc);
    int lane = threadIdx.x & 63, wave = threadIdx.x >> 6;
    int wr = wave >> 1, wc = wave & 1;
    #pragma unroll
    for (int i = 0; i < 4; i++) {
        int mb = m0 + wr*64 + i*16 + (lane>>4)*4;
        #pragma unroll
        for (int j = 0; j < 4; j++) {
            int n = n0 + wc*64 + j*16 + (lane&15);
            float bv = bias[n];
            float sc = z ? 1.0f : fabsf(iscale[n]);
            #pragma unroll
            for (int r = 0; r < 4; r++) {
                float v = acc[i][j][r] + bv;
                outp[(size_t)(mb+r)*DD + n] = z ? v : v*sc;
            }
        }
    }
}

// ACT: 0 none, 1 gelu; RESID adds fp32 resid; OUTBF16 selects output type
template<int ACT, bool RESID, bool OUTBF16>
__global__ __launch_bounds__(256) void mgemm_k(
    const ushort* __restrict__ A, const ushort* __restrict__ Bt,
    const float* __restrict__ bias, const float* __restrict__ resid,
    void* __restrict__ Cout, int N, int K)
{
    __shared__ ushort As[4096], Bs[4096];
    int m0 = blockIdx.y * 128, n0 = blockIdx.x * 128;
    f32x4 acc[4][4] = {};
    mgemm_core(A, Bt, K, m0, n0, As, Bs, acc);
    int lane = threadIdx.x & 63, wave = threadIdx.x >> 6;
    int wr = wave >> 1, wc = wave & 1;
    #pragma unroll
    for (int i = 0; i < 4; i++) {
        int mb = m0 + wr*64 + i*16 + (lane>>4)*4;
        #pragma unroll
        for (int j = 0; j < 4; j++) {
            int n = n0 + wc*64 + j*16 + (lane&15);
            float bv = bias[n];
            #pragma unroll
            for (int r = 0; r < 4; r++) {
                size_t idx = (size_t)(mb + r)*N + n;
                float v = acc[i][j][r] + bv;
                if (ACT==1) v = geluf(v);
                if (RESID) v += resid[idx];
                if (OUTBF16) ((ushort*)Cout)[idx] = f2bf(v);
                else         ((float*)Cout)[idx]  = v;
            }
        }
    }
}

// ---------------- conversions ----------------
__global__ __launch_bounds__(256) void cvt_bf16_k(const float* __restrict__ in, ushort* __restrict__ outp){
    size_t i = ((size_t)blockIdx.x*256 + threadIdx.x)*8;
    float4 a = *(const float4*)(in + i);
    float4 b = *(const float4*)(in + i + 4);
    ushort t[8];
    t[0]=f2bf(a.x); t[1]=f2bf(a.y); t[2]=f2bf(a.z); t[3]=f2bf(a.w);
    t[4]=f2bf(b.x); t[5]=f2bf(b.y); t[6]=f2bf(b.z); t[7]=f2bf(b.w);
    *(int4*)(outp + i) = *(const int4*)t;
}

__device__ __forceinline__ void tcvt_body(const float* W, ushort* Wt, int K, int N){
    __shared__ float tile[32][33];
    int n0 = blockIdx.x*32, k0 = blockIdx.y*32;
    int tx = threadIdx.x & 7, ty = threadIdx.x >> 3;
    float4 v = *(const float4*)(W + (size_t)(k0+ty)*N + n0 + tx*4);
    tile[ty][tx*4+0]=v.x; tile[ty][tx*4+1]=v.y; tile[ty][tx*4+2]=v.z; tile[ty][tx*4+3]=v.w;
    __syncthreads();
    ushort t[4];
    #pragma unroll
    for (int i=0;i<4;i++) t[i] = f2bf(tile[tx*4+i][ty]);
    *(uint2*)(Wt + (size_t)(n0+ty)*K + k0 + tx*4) = *(const uint2*)t;
}

__global__ __launch_bounds__(256) void tcvt_k(const float* __restrict__ W, ushort* __restrict__ Wt, int K, int N){
    tcvt_body(W, Wt, K, N);
}
// two [1024][2048] weights
__global__ __launch_bounds__(256) void tcvt2_k(const float* __restrict__ w0, ushort* __restrict__ o0,
                                               const float* __restrict__ w1, ushort* __restrict__ o1){
    tcvt_body(blockIdx.z ? w1 : w0, blockIdx.z ? o1 : o0, 1024, 2048);
}
// six [1024][1024] weights
__global__ __launch_bounds__(256) void tcvt6_k(
    const float* __restrict__ w0, ushort* __restrict__ o0,
    const float* __restrict__ w1, ushort* __restrict__ o1,
    const float* __restrict__ w2, ushort* __restrict__ o2,
    const float* __restrict__ w3, ushort* __restrict__ o3,
    const float* __restrict__ w4, ushort* __restrict__ o4,
    const float* __restrict__ w5, ushort* __restrict__ o5)
{
    const float* W; ushort* Wt;
    switch(blockIdx.z){
        case 0: W=w0; Wt=o0; break;
        case 1: W=w1; Wt=o1; break;
        case 2: W=w2; Wt=o2; break;
        case 3: W=w3; Wt=o3; break;
        case 4: W=w4; Wt=o4; break;
        default: W=w5; Wt=o5; break;
    }
    tcvt_body(W, Wt, 1024, 1024);
}

// ---------------- scan complex (recompute-on-the-fly) ----------------
// pass A: phi chunk sums (pd is pre-scaled by |iscale|)
__global__ __launch_bounds__(256) void passA_k(
    const float* __restrict__ pd, float* __restrict__ csum)
{
    int d = blockIdx.x*256 + threadIdx.x;
    int c = blockIdx.y, b = blockIdx.z;
    const float* p = pd + ((size_t)b*SS + (size_t)c*CL2)*DD + d;
    float s = 0.f;
    for (int i = 0; i < CL2; i++) s += p[(size_t)i*DD];
    csum[((size_t)b*NC2 + c)*DD + d] = s;
}

// exclusive scan over NC2 chunk-sums; layout [group][NC2][DD]
__global__ void scan2_k(float* __restrict__ csum, int nchains){
    int idx = blockIdx.x*256 + threadIdx.x;
    if (idx >= nchains) return;
    int xg = idx / DD, d = idx % DD;
    float* p = csum + (size_t)xg*NC2*DD + d;
    float run = 0.f;
    for (int c = 0; c < NC2; c++){ float t = p[(size_t)c*DD]; p[(size_t)c*DD] = run; run += t; }
}

// pass B: recompute phi locally; tri chunk sums for (tr,ti,tw)
__global__ __launch_bounds__(256) void passB_k(
    const float* __restrict__ pd, const float* __restrict__ wg,
    const float* __restrict__ mag, const float* __restrict__ x,
    const float* __restrict__ csum_phi, float* __restrict__ csum_tri)
{
    int d = blockIdx.x*256 + threadIdx.x;
    int c = blockIdx.y, b = blockIdx.z;
    size_t off = ((size_t)b*SS + (size_t)c*CL2)*DD + d;
    float ph = csum_phi[((size_t)b*NC2 + c)*DD + d];
    float s0=0.f, s1=0.f, s2=0.f;
    for (int i = 0; i < CL2; i++){
        size_t o = off + (size_t)i*DD;
        ph += pd[o];
        float w = wg[o], m = mag[o];
        float ct = w*x[o]*m;
        float sp, cp; sincosf(ph, &sp, &cp);
        s0 += ct*cp; s1 += ct*sp; s2 += fmaf(w, m, 1e-8f);
    }
    size_t cs = ((size_t)b*NC2 + c)*DD + d;
    size_t G = (size_t)BB*NC2*DD;
    csum_tri[cs]=s0; csum_tri[G+cs]=s1; csum_tri[2*G+cs]=s2;
}

// pass C: recompute everything, running cumsums, retrieval+mix -> ret
__global__ __launch_bounds__(256) void passC_k(
    const float* __restrict__ pd, const float* __restrict__ wg,
    const float* __restrict__ mag, const float* __restrict__ x,
    const float* __restrict__ qadj, const float* __restrict__ mixb,
    const float* __restrict__ csum_phi, const float* __restrict__ csum_tri,
    float* __restrict__ ret)
{
    int d = blockIdx.x*256 + threadIdx.x;
    int c = blockIdx.y, b = blockIdx.z;
    size_t off = ((size_t)b*SS + (size_t)c*CL2)*DD + d;
    size_t cs = ((size_t)b*NC2 + c)*DD + d;
    size_t G = (size_t)BB*NC2*DD;
    float ph = csum_phi[cs];
    float r0 = csum_tri[cs], r1 = csum_tri[G+cs], r2 = csum_tri[2*G+cs];
    size_t row0 = (size_t)b*SS + (size_t)c*CL2;
    for (int i = 0; i < CL2; i++){
        size_t o = off + (size_t)i*DD;
        ph += pd[o];
        float w = wg[o], m = mag[o];
        float ct = w*x[o]*m;
        float sp, cp; sincosf(ph, &sp, &cp);
        r0 += ct*cp; r1 += ct*sp; r2 += fmaf(w, m, 1e-8f);
        float inv = rsqrtf(r2);
        float mr = r0*inv, mi = r1*inv;
        float q = ph + qadj[o];
        float sq, cq; sincosf(q, &sq, &cq);
        float rr = mr*cq + mi*sq;
        float ri = mi*cq - mr*sq;
        size_t mb = (row0 + i)*D2 + d;
        ret[o] = mixb[mb]*rr + mixb[mb+DD]*ri;
    }
}

// LayerNorm over d per row; bf16 out
__global__ __launch_bounds__(256) void ln_k(
    const float* __restrict__ ret, const float* __restrict__ ln_g,
    const float* __restrict__ ln_b, ushort* __restrict__ outp)
{
    int row = blockIdx.x;
    size_t base = (size_t)row*DD;
    float vals[4];
    float sum=0.f, sumsq=0.f;
    #pragma unroll
    for (int k = 0; k < 4; k++){
        int d = threadIdx.x + k*256;
        float v = ret[base+d];
        vals[k]=v; sum+=v; sumsq = fmaf(v,v,sumsq);
    }
    #pragma unroll
    for (int off=32; off; off>>=1){
        sum   += __shfl_down(sum,off);
        sumsq += __shfl_down(sumsq,off);
    }
    __shared__ float red[8];
    int lane = threadIdx.x & 63, wid = threadIdx.x >> 6;
    if (lane==0){ red[wid]=sum; red[4+wid]=sumsq; }
    __syncthreads();
    sum   = red[0]+red[1]+red[2]+red[3];
    sumsq = red[4]+red[5]+red[6]+red[7];
    float mu  = sum * (1.0f/DD);
    float var = sumsq*(1.0f/DD) - mu*mu;
    float rstd = rsqrtf(var + 1e-5f);
    #pragma unroll
    for (int k = 0; k < 4; k++){
        int d = threadIdx.x + k*256;
        outp[base+d] = f2bf((vals[k]-mu)*rstd*ln_g[d] + ln_b[d]);
    }
}

extern "C" void kernel_launch(void* const* d_in, const int* in_sizes, int n_in,
                              void* d_out, int out_size, void* d_ws, size_t ws_size,
                              hipStream_t stream)
{
    const float* x     = (const float*)d_in[0];
    const float* w_pt1 = (const float*)d_in[1];
    const float* b_pt1 = (const float*)d_in[2];
    const float* w_pt2 = (const float*)d_in[3];
    const float* b_pt2 = (const float*)d_in[4];
    const float* iscale= (const float*)d_in[5];
    const float* w_wg  = (const float*)d_in[6];
    const float* b_wg  = (const float*)d_in[7];
    const float* gtemp = (const float*)d_in[8];
    const float* w_mag = (const float*)d_in[9];
    const float* b_mag = (const float*)d_in[10];
    const float* w_q1  = (const float*)d_in[11];
    const float* b_q1  = (const float*)d_in[12];
    const float* w_q2  = (const float*)d_in[13];
    const float* b_q2  = (const float*)d_in[14];
    const float* w_mix = (const float*)d_in[15];
    const float* b_mix = (const float*)d_in[16];
    const float* ln_g  = (const float*)d_in[17];
    const float* ln_b  = (const float*)d_in[18];
    const float* w_o1  = (const float*)d_in[19];
    const float* b_o1  = (const float*)d_in[20];
    const float* w_o2  = (const float*)d_in[21];
    const float* b_o2  = (const float*)d_in[22];
    float* out = (float*)d_out;

    float* ws = (float*)d_ws;
    const size_t SZ = (size_t)MTOT*DD;     // 4M elems
    float* pd    = ws;                     // SZ
    float* wgf   = ws + SZ;                // SZ   (later: Hob bf16)
    float* magf  = ws + 2*SZ;              // SZ
    float* qadj  = ws + 3*SZ;              // SZ
    float* mixb  = ws + 4*SZ;              // 2SZ
    ushort* xb   = (ushort*)(ws + 6*SZ);   // SZ ushorts -> 0.5 SZ floats
    ushort* H1b  = (ushort*)(ws + 6*SZ + SZ/2);   // 2SZ ushorts -> SZ floats
    float*  ret  = (float*)H1b;            // alias: H1b dead after GEMM-BC
    ushort* Hqb  = (ushort*)(ws + 6*SZ + SZ/2 + SZ);  // SZ ushorts
    ushort* lnb  = Hqb;                    // alias: Hqb dead after GEMM-BC
    ushort* Hob  = (ushort*)wgf;           // alias: wgf dead after passC
    ushort* wtu  = (ushort*)(ws + 8*SZ + SZ/2);
    ushort* Wt_all = wtu;                          // [7168][1024]
    ushort* wt_pt2 = wtu + (size_t)7168*1024;      // [1024][2048]
    ushort* wt_q2  = wt_pt2 + (size_t)1024*2048;   // [1024][1024]
    ushort* wt_o1  = wt_q2  + (size_t)1024*1024;
    ushort* wt_o2  = wt_o1  + (size_t)1024*1024;
    float* csum_phi = (float*)(wt_o2 + (size_t)1024*1024); // BB*NC2*DD
    float* csum_tri = csum_phi + (size_t)BB*NC2*DD;        // 3x

    dim3 blk(256);
    // conversions
    cvt_bf16_k<<<dim3(SZ/2048), blk, 0, stream>>>(x, xb);
    tcvt2_k<<<dim3(64, 32, 2), blk, 0, stream>>>(w_pt1, Wt_all, w_mix, Wt_all + (size_t)5120*1024);
    tcvt6_k<<<dim3(32, 32, 6), blk, 0, stream>>>(
        w_wg,  Wt_all + (size_t)2048*1024,
        w_mag, Wt_all + (size_t)3072*1024,
        w_q1,  Wt_all + (size_t)4096*1024,
        w_q2,  wt_q2,  w_o1, wt_o1,  w_o2, wt_o2);
    tcvt_k<<<dim3(32, 64), blk, 0, stream>>>(w_pt2, wt_pt2, 2048, 1024);
    // fused GEMM A: all x-consuming projections
    mgemmA_k<<<dim3(56, 32), blk, 0, stream>>>(xb, Wt_all, b_pt1, b_wg, b_mag, b_q1, b_mix,
                                               gtemp, H1b, wgf, magf, Hqb, mixb);
    // GEMM B/C: pd (pre-scaled by |iscale|) and qadj
    mgemmBC_k<<<dim3(8, 32, 2), blk, 0, stream>>>(H1b, wt_pt2, Hqb, wt_q2, b_pt2, b_q2,
                                                  iscale, pd, qadj);
    // scan complex
    passA_k<<<dim3(DD/256, NC2, BB), blk, 0, stream>>>(pd, csum_phi);
    scan2_k<<<dim3((BB*DD+255)/256), blk, 0, stream>>>(csum_phi, BB*DD);
    passB_k<<<dim3(DD/256, NC2, BB), blk, 0, stream>>>(pd, wgf, magf, x, csum_phi, csum_tri);
    scan2_k<<<dim3((3*BB*DD+255)/256), blk, 0, stream>>>(csum_tri, 3*BB*DD);
    passC_k<<<dim3(DD/256, NC2, BB), blk, 0, stream>>>(pd, wgf, magf, x, qadj, mixb,
                                                       csum_phi, csum_tri, ret);
    ln_k<<<dim3(MTOT), blk, 0, stream>>>(ret, ln_g, ln_b, lnb);
    // output head
    mgemm_k<1,false,true><<<dim3(8,32), blk, 0, stream>>>(lnb, wt_o1, b_o1, nullptr, Hob, DD, DD);
    mgemm_k<0,true,false><<<dim3(8,32), blk, 0, stream>>>(Hob, wt_o2, b_o2, x, out, DD, DD);
}

// Round 4
// 340.118 us; speedup vs baseline: 1.1149x; 1.1149x over previous
//
#include <hip/hip_runtime.h>
#include <hip/hip_bf16.h>

#define MTOT 4096   // B*S
#define DD   1024
#define D2   2048
#define SS   2048
#define BB   2
#define NC2  64
#define CL2  (SS/NC2)   // 32

typedef __attribute__((ext_vector_type(8))) short bf16x8;
typedef __attribute__((ext_vector_type(4))) float f32x4;

__device__ __forceinline__ float sigmf(float v){
    return 1.0f/(1.0f+__expf(-v));
}
// tanh-form GELU (max |err| vs erf-form ~3e-3, far under bf16 noise here)
__device__ __forceinline__ float geluf(float v){
    float u = 0.7978845608f*v*(1.0f + 0.044715f*v*v);
    float e = __expf(2.0f*u);
    float t = 1.0f - 2.0f/(e + 1.0f);
    return 0.5f*v*(1.0f + t);
}
__device__ __forceinline__ ushort f2bf(float f){
    unsigned u = __float_as_uint(f);
    unsigned r = (u + 0x7FFF + ((u>>16)&1)) >> 16;
    return (ushort)r;
}
__device__ __forceinline__ float bf2f(ushort u){
    return __uint_as_float(((unsigned)u)<<16);
}

// ---------------- bf16 MFMA GEMM core (m97 structure) ----------------
__device__ __forceinline__ void mgemm_core(
    const ushort* __restrict__ A, const ushort* __restrict__ Bt, int K,
    int m0, int n0, ushort* As, ushort* Bs, f32x4 (&acc)[4][4])
{
    int tid  = threadIdx.x;
    int lane = tid & 63, wave = tid >> 6;
    int wr = wave >> 1, wc = wave & 1;
    int lrow = lane & 15, lk8 = (lane >> 4) << 3;
    for (int k0 = 0; k0 < K; k0 += 32) {
        __syncthreads();
        #pragma unroll
        for (int i = 0; i < 2; i++) {
            int e = (i*256 + tid) * 8;
            int r = e >> 5, c = e & 31;
            __builtin_amdgcn_global_load_lds(
                (const __attribute__((address_space(1))) void*)(A + (size_t)(m0 + r)*K + k0 + c),
                (__attribute__((address_space(3))) void*)(As + e), 16, 0, 0);
            __builtin_amdgcn_global_load_lds(
                (const __attribute__((address_space(1))) void*)(Bt + (size_t)(n0 + r)*K + k0 + c),
                (__attribute__((address_space(3))) void*)(Bs + e), 16, 0, 0);
        }
        __syncthreads();
        bf16x8 af[4], bfr[4];
        #pragma unroll
        for (int i = 0; i < 4; i++) {
            af[i]  = *(const bf16x8*)(As + (wr*64 + i*16 + lrow)*32 + lk8);
            bfr[i] = *(const bf16x8*)(Bs + (wc*64 + i*16 + lrow)*32 + lk8);
        }
        #pragma unroll
        for (int i = 0; i < 4; i++)
            #pragma unroll
            for (int j = 0; j < 4; j++)
                acc[i][j] = __builtin_amdgcn_mfma_f32_16x16x32_bf16(af[i], bfr[j], acc[i][j], 0, 0, 0);
    }
}

// Fused GEMM A: xb @ [w_pt1 | w_wg | w_mag | w_q1 | w_mix], N=7168, K=1024.
// 1D grid 1792; XCD k owns m-tiles [4k,4k+4) (A L2-resident), streams n.
__global__ __launch_bounds__(256) void mgemmA_k(
    const ushort* __restrict__ xb, const ushort* __restrict__ Wt,
    const float* __restrict__ b_pt1, const float* __restrict__ b_wg,
    const float* __restrict__ b_mag, const float* __restrict__ b_q1,
    const float* __restrict__ b_mix, const float* __restrict__ gtemp,
    ushort* __restrict__ H1b, ushort* __restrict__ wgb, ushort* __restrict__ magb,
    ushort* __restrict__ Hqb, ushort* __restrict__ mixb)
{
    __shared__ ushort As[4096], Bs[4096];
    int bid = blockIdx.x;
    int xcd = bid & 7, local = bid >> 3;          // local in [0,224)
    int m0 = (xcd*4 + (local & 3)) * 128;
    int n0 = (local >> 2) * 128;                  // 56 n-panels
    f32x4 acc[4][4] = {};
    mgemm_core(xb, Wt, 1024, m0, n0, As, Bs, acc);
    int lane = threadIdx.x & 63, wave = threadIdx.x >> 6;
    int wr = wave >> 1, wc = wave & 1;
    int rng = n0 >> 10;           // 0,1:pt1  2:wg  3:mag  4:q1  5,6:mix
    float gt = gtemp[0];
    #pragma unroll
    for (int i = 0; i < 4; i++) {
        int mb = m0 + wr*64 + i*16 + (lane>>4)*4;
        #pragma unroll
        for (int j = 0; j < 4; j++) {
            int n = n0 + wc*64 + j*16 + (lane&15);
            #pragma unroll
            for (int r = 0; r < 4; r++) {
                int m = mb + r;
                float v = acc[i][j][r];
                if (rng < 2) {
                    H1b[(size_t)m*D2 + n] = f2bf(geluf(v + b_pt1[n]));
                } else if (rng == 2) {
                    wgb[(size_t)m*DD + n-2048] = f2bf(sigmf((v + b_wg[n-2048])*gt));
                } else if (rng == 3) {
                    magb[(size_t)m*DD + n-3072] = f2bf(sigmf(v + b_mag[n-3072])*5.0f);
                } else if (rng == 4) {
                    Hqb[(size_t)m*DD + n-4096] = f2bf(geluf(v + b_q1[n-4096]));
                } else {
                    mixb[(size_t)m*D2 + n-5120] = f2bf(sigmf(v + b_mix[n-5120]));
                }
            }
        }
    }
}

// z=0: pd = (H1 @ w_pt2 + b_pt2) * |iscale| (K=2048);  z=1: qadj = Hq @ w_q2 + b_q2 (K=1024)
// 1D grid 512; XCD k owns m-tiles [4k,4k+4), streams n for both z.
__global__ __launch_bounds__(256) void mgemmBC_k(
    const ushort* __restrict__ H1b, const ushort* __restrict__ wt_pt2,
    const ushort* __restrict__ Hqb, const ushort* __restrict__ wt_q2,
    const float* __restrict__ b_pt2, const float* __restrict__ b_q2,
    const float* __restrict__ iscale,
    float* __restrict__ pd, float* __restrict__ qadj)
{
    __shared__ ushort As[4096], Bs[4096];
    int bid = blockIdx.x;
    int xcd = bid & 7, local = bid >> 3;          // [0,64)
    int m0 = (xcd*4 + (local & 3)) * 128;
    int rest = local >> 2;                        // [0,16)
    int z = rest >> 3;
    int n0 = (rest & 7) * 128;
    const ushort* A  = z ? Hqb   : H1b;
    const ushort* Bt = z ? wt_q2 : wt_pt2;
    const float* bias = z ? b_q2 : b_pt2;
    int K = z ? 1024 : 2048;
    float* outp = z ? qadj : pd;
    f32x4 acc[4][4] = {};
    mgemm_core(A, Bt, K, m0, n0, As, Bs, acc);
    int lane = threadIdx.x & 63, wave = threadIdx.x >> 6;
    int wr = wave >> 1, wc = wave & 1;
    #pragma unroll
    for (int i = 0; i < 4; i++) {
        int mb = m0 + wr*64 + i*16 + (lane>>4)*4;
        #pragma unroll
        for (int j = 0; j < 4; j++) {
            int n = n0 + wc*64 + j*16 + (lane&15);
            float bv = bias[n];
            float sc = z ? 1.0f : fabsf(iscale[n]);
            #pragma unroll
            for (int r = 0; r < 4; r++) {
                float v = acc[i][j][r] + bv;
                outp[(size_t)(mb+r)*DD + n] = z ? v : v*sc;
            }
        }
    }
}

// head GEMMs; 1D grid 256; ACT 0/1, RESID, OUTBF16 as before
template<int ACT, bool RESID, bool OUTBF16>
__global__ __launch_bounds__(256) void mgemm_k(
    const ushort* __restrict__ A, const ushort* __restrict__ Bt,
    const float* __restrict__ bias, const float* __restrict__ resid,
    void* __restrict__ Cout, int N, int K)
{
    __shared__ ushort As[4096], Bs[4096];
    int bid = blockIdx.x;
    int xcd = bid & 7, local = bid >> 3;          // [0,32)
    int m0 = (xcd*4 + (local & 3)) * 128;
    int n0 = (local >> 2) * 128;                  // 8 n-panels
    f32x4 acc[4][4] = {};
    mgemm_core(A, Bt, K, m0, n0, As, Bs, acc);
    int lane = threadIdx.x & 63, wave = threadIdx.x >> 6;
    int wr = wave >> 1, wc = wave & 1;
    #pragma unroll
    for (int i = 0; i < 4; i++) {
        int mb = m0 + wr*64 + i*16 + (lane>>4)*4;
        #pragma unroll
        for (int j = 0; j < 4; j++) {
            int n = n0 + wc*64 + j*16 + (lane&15);
            float bv = bias[n];
            #pragma unroll
            for (int r = 0; r < 4; r++) {
                size_t idx = (size_t)(mb + r)*N + n;
                float v = acc[i][j][r] + bv;
                if (ACT==1) v = geluf(v);
                if (RESID) v += resid[idx];
                if (OUTBF16) ((ushort*)Cout)[idx] = f2bf(v);
                else         ((float*)Cout)[idx]  = v;
            }
        }
    }
}

// ---------------- conversions ----------------
__global__ __launch_bounds__(256) void cvt_bf16_k(const float* __restrict__ in, ushort* __restrict__ outp){
    size_t i = ((size_t)blockIdx.x*256 + threadIdx.x)*8;
    float4 a = *(const float4*)(in + i);
    float4 b = *(const float4*)(in + i + 4);
    ushort t[8];
    t[0]=f2bf(a.x); t[1]=f2bf(a.y); t[2]=f2bf(a.z); t[3]=f2bf(a.w);
    t[4]=f2bf(b.x); t[5]=f2bf(b.y); t[6]=f2bf(b.z); t[7]=f2bf(b.w);
    *(int4*)(outp + i) = *(const int4*)t;
}

__device__ __forceinline__ void tcvt_body(const float* W, ushort* Wt, int K, int N){
    __shared__ float tile[32][33];
    int n0 = blockIdx.x*32, k0 = blockIdx.y*32;
    int tx = threadIdx.x & 7, ty = threadIdx.x >> 3;
    float4 v = *(const float4*)(W + (size_t)(k0+ty)*N + n0 + tx*4);
    tile[ty][tx*4+0]=v.x; tile[ty][tx*4+1]=v.y; tile[ty][tx*4+2]=v.z; tile[ty][tx*4+3]=v.w;
    __syncthreads();
    ushort t[4];
    #pragma unroll
    for (int i=0;i<4;i++) t[i] = f2bf(tile[tx*4+i][ty]);
    *(uint2*)(Wt + (size_t)(n0+ty)*K + k0 + tx*4) = *(const uint2*)t;
}

__global__ __launch_bounds__(256) void tcvt_k(const float* __restrict__ W, ushort* __restrict__ Wt, int K, int N){
    tcvt_body(W, Wt, K, N);
}
__global__ __launch_bounds__(256) void tcvt2_k(const float* __restrict__ w0, ushort* __restrict__ o0,
                                               const float* __restrict__ w1, ushort* __restrict__ o1){
    tcvt_body(blockIdx.z ? w1 : w0, blockIdx.z ? o1 : o0, 1024, 2048);
}
__global__ __launch_bounds__(256) void tcvt6_k(
    const float* __restrict__ w0, ushort* __restrict__ o0,
    const float* __restrict__ w1, ushort* __restrict__ o1,
    const float* __restrict__ w2, ushort* __restrict__ o2,
    const float* __restrict__ w3, ushort* __restrict__ o3,
    const float* __restrict__ w4, ushort* __restrict__ o4,
    const float* __restrict__ w5, ushort* __restrict__ o5)
{
    const float* W; ushort* Wt;
    switch(blockIdx.z){
        case 0: W=w0; Wt=o0; break;
        case 1: W=w1; Wt=o1; break;
        case 2: W=w2; Wt=o2; break;
        case 3: W=w3; Wt=o3; break;
        case 4: W=w4; Wt=o4; break;
        default: W=w5; Wt=o5; break;
    }
    tcvt_body(W, Wt, 1024, 1024);
}

// ---------------- scan complex (recompute-on-the-fly) ----------------
__global__ __launch_bounds__(256) void passA_k(
    const float* __restrict__ pd, float* __restrict__ csum)
{
    int d = blockIdx.x*256 + threadIdx.x;
    int c = blockIdx.y, b = blockIdx.z;
    const float* p = pd + ((size_t)b*SS + (size_t)c*CL2)*DD + d;
    float s = 0.f;
    for (int i = 0; i < CL2; i++) s += p[(size_t)i*DD];
    csum[((size_t)b*NC2 + c)*DD + d] = s;
}

__global__ void scan2_k(float* __restrict__ csum, int nchains){
    int idx = blockIdx.x*256 + threadIdx.x;
    if (idx >= nchains) return;
    int xg = idx / DD, d = idx % DD;
    float* p = csum + (size_t)xg*NC2*DD + d;
    float run = 0.f;
    for (int c = 0; c < NC2; c++){ float t = p[(size_t)c*DD]; p[(size_t)c*DD] = run; run += t; }
}

__global__ __launch_bounds__(256) void passB_k(
    const float* __restrict__ pd, const ushort* __restrict__ wgb,
    const ushort* __restrict__ magb, const float* __restrict__ x,
    const float* __restrict__ csum_phi, float* __restrict__ csum_tri)
{
    int d = blockIdx.x*256 + threadIdx.x;
    int c = blockIdx.y, b = blockIdx.z;
    size_t off = ((size_t)b*SS + (size_t)c*CL2)*DD + d;
    float ph = csum_phi[((size_t)b*NC2 + c)*DD + d];
    float s0=0.f, s1=0.f, s2=0.f;
    for (int i = 0; i < CL2; i++){
        size_t o = off + (size_t)i*DD;
        ph += pd[o];
        float w = bf2f(wgb[o]), m = bf2f(magb[o]);
        float ct = w*x[o]*m;
        float sp, cp; sincosf(ph, &sp, &cp);
        s0 += ct*cp; s1 += ct*sp; s2 += fmaf(w, m, 1e-8f);
    }
    size_t cs = ((size_t)b*NC2 + c)*DD + d;
    size_t G = (size_t)BB*NC2*DD;
    csum_tri[cs]=s0; csum_tri[G+cs]=s1; csum_tri[2*G+cs]=s2;
}

__global__ __launch_bounds__(256) void passC_k(
    const float* __restrict__ pd, const ushort* __restrict__ wgb,
    const ushort* __restrict__ magb, const float* __restrict__ x,
    const float* __restrict__ qadj, const ushort* __restrict__ mixb,
    const float* __restrict__ csum_phi, const float* __restrict__ csum_tri,
    ushort* __restrict__ ret)
{
    int d = blockIdx.x*256 + threadIdx.x;
    int c = blockIdx.y, b = blockIdx.z;
    size_t off = ((size_t)b*SS + (size_t)c*CL2)*DD + d;
    size_t cs = ((size_t)b*NC2 + c)*DD + d;
    size_t G = (size_t)BB*NC2*DD;
    float ph = csum_phi[cs];
    float r0 = csum_tri[cs], r1 = csum_tri[G+cs], r2 = csum_tri[2*G+cs];
    size_t row0 = (size_t)b*SS + (size_t)c*CL2;
    for (int i = 0; i < CL2; i++){
        size_t o = off + (size_t)i*DD;
        ph += pd[o];
        float w = bf2f(wgb[o]), m = bf2f(magb[o]);
        float ct = w*x[o]*m;
        float sp, cp; sincosf(ph, &sp, &cp);
        r0 += ct*cp; r1 += ct*sp; r2 += fmaf(w, m, 1e-8f);
        float inv = rsqrtf(r2);
        float mr = r0*inv, mi = r1*inv;
        float q = ph + qadj[o];
        float sq, cq; sincosf(q, &sq, &cq);
        float rr = mr*cq + mi*sq;
        float ri = mi*cq - mr*sq;
        size_t mb2 = (row0 + i)*D2 + d;
        ret[o] = f2bf(bf2f(mixb[mb2])*rr + bf2f(mixb[mb2+DD])*ri);
    }
}

// LayerNorm over d per row; bf16 in/out
__global__ __launch_bounds__(256) void ln_k(
    const ushort* __restrict__ ret, const float* __restrict__ ln_g,
    const float* __restrict__ ln_b, ushort* __restrict__ outp)
{
    int row = blockIdx.x;
    size_t base = (size_t)row*DD;
    float vals[4];
    float sum=0.f, sumsq=0.f;
    #pragma unroll
    for (int k = 0; k < 4; k++){
        int d = threadIdx.x + k*256;
        float v = bf2f(ret[base+d]);
        vals[k]=v; sum+=v; sumsq = fmaf(v,v,sumsq);
    }
    #pragma unroll
    for (int off=32; off; off>>=1){
        sum   += __shfl_down(sum,off);
        sumsq += __shfl_down(sumsq,off);
    }
    __shared__ float red[8];
    int lane = threadIdx.x & 63, wid = threadIdx.x >> 6;
    if (lane==0){ red[wid]=sum; red[4+wid]=sumsq; }
    __syncthreads();
    sum   = red[0]+red[1]+red[2]+red[3];
    sumsq = red[4]+red[5]+red[6]+red[7];
    float mu  = sum * (1.0f/DD);
    float var = sumsq*(1.0f/DD) - mu*mu;
    float rstd = rsqrtf(var + 1e-5f);
    #pragma unroll
    for (int k = 0; k < 4; k++){
        int d = threadIdx.x + k*256;
        outp[base+d] = f2bf((vals[k]-mu)*rstd*ln_g[d] + ln_b[d]);
    }
}

extern "C" void kernel_launch(void* const* d_in, const int* in_sizes, int n_in,
                              void* d_out, int out_size, void* d_ws, size_t ws_size,
                              hipStream_t stream)
{
    const float* x     = (const float*)d_in[0];
    const float* w_pt1 = (const float*)d_in[1];
    const float* b_pt1 = (const float*)d_in[2];
    const float* w_pt2 = (const float*)d_in[3];
    const float* b_pt2 = (const float*)d_in[4];
    const float* iscale= (const float*)d_in[5];
    const float* w_wg  = (const float*)d_in[6];
    const float* b_wg  = (const float*)d_in[7];
    const float* gtemp = (const float*)d_in[8];
    const float* w_mag = (const float*)d_in[9];
    const float* b_mag = (const float*)d_in[10];
    const float* w_q1  = (const float*)d_in[11];
    const float* b_q1  = (const float*)d_in[12];
    const float* w_q2  = (const float*)d_in[13];
    const float* b_q2  = (const float*)d_in[14];
    const float* w_mix = (const float*)d_in[15];
    const float* b_mix = (const float*)d_in[16];
    const float* ln_g  = (const float*)d_in[17];
    const float* ln_b  = (const float*)d_in[18];
    const float* w_o1  = (const float*)d_in[19];
    const float* b_o1  = (const float*)d_in[20];
    const float* w_o2  = (const float*)d_in[21];
    const float* b_o2  = (const float*)d_in[22];
    float* out = (float*)d_out;

    const size_t SZ = (size_t)MTOT*DD;     // 4M elems
    ushort* u = (ushort*)d_ws;
    ushort* xb    = u;                 u += SZ;        // bf16 x
    ushort* H1b   = u;                 u += 2*SZ;      // [4096][2048]
    ushort* ret   = H1b;                                // alias (H1b dead after BC)
    ushort* Hqb   = u;                 u += SZ;
    ushort* lnb   = Hqb;                                // alias (Hqb dead after BC)
    ushort* wgb   = u;                 u += SZ;
    ushort* magb  = u;                 u += SZ;
    ushort* mixb  = u;                 u += 2*SZ;      // [4096][2048]
    ushort* Hob   = u;                 u += SZ;
    float*  pd    = (float*)u;         u += 2*SZ;      // fp32
    float*  qadj  = (float*)u;         u += 2*SZ;      // fp32
    ushort* Wt_all= u;                 u += (size_t)7168*1024;
    ushort* wt_pt2= u;                 u += (size_t)1024*2048;
    ushort* wt_q2 = u;                 u += (size_t)1024*1024;
    ushort* wt_o1 = u;                 u += (size_t)1024*1024;
    ushort* wt_o2 = u;                 u += (size_t)1024*1024;
    float* csum_phi = (float*)u;                       // BB*NC2*DD
    float* csum_tri = csum_phi + (size_t)BB*NC2*DD;    // 3x

    dim3 blk(256);
    // conversions
    cvt_bf16_k<<<dim3(SZ/2048), blk, 0, stream>>>(x, xb);
    tcvt2_k<<<dim3(64, 32, 2), blk, 0, stream>>>(w_pt1, Wt_all, w_mix, Wt_all + (size_t)5120*1024);
    tcvt6_k<<<dim3(32, 32, 6), blk, 0, stream>>>(
        w_wg,  Wt_all + (size_t)2048*1024,
        w_mag, Wt_all + (size_t)3072*1024,
        w_q1,  Wt_all + (size_t)4096*1024,
        w_q2,  wt_q2,  w_o1, wt_o1,  w_o2, wt_o2);
    tcvt_k<<<dim3(32, 64), blk, 0, stream>>>(w_pt2, wt_pt2, 2048, 1024);
    // fused GEMM A (1792 blocks, XCD-chunked)
    mgemmA_k<<<dim3(1792), blk, 0, stream>>>(xb, Wt_all, b_pt1, b_wg, b_mag, b_q1, b_mix,
                                             gtemp, H1b, wgb, magb, Hqb, mixb);
    // GEMM B/C (512 blocks)
    mgemmBC_k<<<dim3(512), blk, 0, stream>>>(H1b, wt_pt2, Hqb, wt_q2, b_pt2, b_q2,
                                             iscale, pd, qadj);
    // scan complex
    passA_k<<<dim3(DD/256, NC2, BB), blk, 0, stream>>>(pd, csum_phi);
    scan2_k<<<dim3((BB*DD+255)/256), blk, 0, stream>>>(csum_phi, BB*DD);
    passB_k<<<dim3(DD/256, NC2, BB), blk, 0, stream>>>(pd, wgb, magb, x, csum_phi, csum_tri);
    scan2_k<<<dim3((3*BB*DD+255)/256), blk, 0, stream>>>(csum_tri, 3*BB*DD);
    passC_k<<<dim3(DD/256, NC2, BB), blk, 0, stream>>>(pd, wgb, magb, x, qadj, mixb,
                                                       csum_phi, csum_tri, ret);
    ln_k<<<dim3(MTOT), blk, 0, stream>>>(ret, ln_g, ln_b, lnb);
    // output head (256 blocks each)
    mgemm_k<1,false,true><<<dim3(256), blk, 0, stream>>>(lnb, wt_o1, b_o1, nullptr, Hob, DD, DD);
    mgemm_k<0,true,false><<<dim3(256), blk, 0, stream>>>(Hob, wt_o2, b_o2, x, out, DD, DD);
}

// Round 5
// 281.396 us; speedup vs baseline: 1.3475x; 1.2087x over previous
//
#include <hip/hip_runtime.h>
#include <hip/hip_bf16.h>

#define MTOT 4096   // B*S
#define DD   1024
#define D2   2048
#define SS   2048
#define BB   2
#define NC2  64
#define CL2  (SS/NC2)   // 32

typedef __attribute__((ext_vector_type(8))) short bf16x8;
typedef __attribute__((ext_vector_type(4))) float f32x4;

__device__ __forceinline__ float sigmf(float v){
    return 1.0f/(1.0f+__expf(-v));
}
// tanh-form GELU (max |err| vs erf-form ~3e-3, far under bf16 noise here)
__device__ __forceinline__ float geluf(float v){
    float u = 0.7978845608f*v*(1.0f + 0.044715f*v*v);
    float e = __expf(2.0f*u);
    float t = 1.0f - 2.0f/(e + 1.0f);
    return 0.5f*v*(1.0f + t);
}
__device__ __forceinline__ ushort f2bf(float f){
    unsigned u = __float_as_uint(f);
    unsigned r = (u + 0x7FFF + ((u>>16)&1)) >> 16;
    return (ushort)r;
}
__device__ __forceinline__ float bf2f(ushort u){
    return __uint_as_float(((unsigned)u)<<16);
}

// ---------------- bf16 MFMA GEMM core: 2-phase double-buffered ----------------
// A: bf16 [M][K] row-major.  Bt: bf16 [N][K].  128x128 tile, 4 waves,
// each wave 64x64 = 4x4 fragments of 16x16x32 MFMA. BK=32, LDS dbuf.
__device__ __forceinline__ void stage_tile(
    const ushort* __restrict__ A, const ushort* __restrict__ Bt, int K,
    int m0, int n0, int k0, ushort* As, ushort* Bs)
{
    int tid = threadIdx.x;
    #pragma unroll
    for (int i = 0; i < 2; i++) {
        int e = (i*256 + tid) * 8;          // elem in [128][32] tile
        int r = e >> 5, c = e & 31;
        __builtin_amdgcn_global_load_lds(
            (const __attribute__((address_space(1))) void*)(A + (size_t)(m0 + r)*K + k0 + c),
            (__attribute__((address_space(3))) void*)(As + e), 16, 0, 0);
        __builtin_amdgcn_global_load_lds(
            (const __attribute__((address_space(1))) void*)(Bt + (size_t)(n0 + r)*K + k0 + c),
            (__attribute__((address_space(3))) void*)(Bs + e), 16, 0, 0);
    }
}

__device__ __forceinline__ void compute_step(
    const ushort* As, const ushort* Bs, int wr, int wc, int lrow, int lk8,
    f32x4 (&acc)[4][4])
{
    bf16x8 af[4], bfr[4];
    #pragma unroll
    for (int i = 0; i < 4; i++) {
        af[i]  = *(const bf16x8*)(As + (wr*64 + i*16 + lrow)*32 + lk8);
        bfr[i] = *(const bf16x8*)(Bs + (wc*64 + i*16 + lrow)*32 + lk8);
    }
    #pragma unroll
    for (int i = 0; i < 4; i++)
        #pragma unroll
        for (int j = 0; j < 4; j++)
            acc[i][j] = __builtin_amdgcn_mfma_f32_16x16x32_bf16(af[i], bfr[j], acc[i][j], 0, 0, 0);
}

__device__ __forceinline__ void mgemm_core(
    const ushort* __restrict__ A, const ushort* __restrict__ Bt, int K,
    int m0, int n0, ushort (&As)[2][4096], ushort (&Bs)[2][4096], f32x4 (&acc)[4][4])
{
    int lane = threadIdx.x & 63, wave = threadIdx.x >> 6;
    int wr = wave >> 1, wc = wave & 1;
    int lrow = lane & 15, lk8 = (lane >> 4) << 3;
    // prologue: stage tile 0, drain (implicit vmcnt(0) in barrier)
    stage_tile(A, Bt, K, m0, n0, 0, As[0], Bs[0]);
    __syncthreads();
    int NT = K >> 5;
    int cur = 0;
    // steady state: issue prefetch of t+1 BEFORE computing t; the
    // end-of-iteration barrier's implicit vmcnt(0)+lgkmcnt(0) drain retires
    // the prefetch after it hid under ds_read+MFMA of tile t.
    for (int t = 0; t < NT-1; t++) {
        stage_tile(A, Bt, K, m0, n0, (t+1) << 5, As[cur^1], Bs[cur^1]);
        compute_step(As[cur], Bs[cur], wr, wc, lrow, lk8, acc);
        __syncthreads();
        cur ^= 1;
    }
    compute_step(As[cur], Bs[cur], wr, wc, lrow, lk8, acc);
}

// Fused GEMM A: xb @ [w_pt1 | w_wg | w_mag | w_q1 | w_mix], N=7168, K=1024.
// 1D grid 1792; XCD k owns m-tiles [4k,4k+4) (A L2-resident), streams n.
__global__ __launch_bounds__(256,4) void mgemmA_k(
    const ushort* __restrict__ xb, const ushort* __restrict__ Wt,
    const float* __restrict__ b_pt1, const float* __restrict__ b_wg,
    const float* __restrict__ b_mag, const float* __restrict__ b_q1,
    const float* __restrict__ b_mix, const float* __restrict__ gtemp,
    ushort* __restrict__ H1b, ushort* __restrict__ wgb, ushort* __restrict__ magb,
    ushort* __restrict__ Hqb, ushort* __restrict__ mixb)
{
    __shared__ ushort As[2][4096], Bs[2][4096];
    int bid = blockIdx.x;
    int xcd = bid & 7, local = bid >> 3;          // local in [0,224)
    int m0 = (xcd*4 + (local & 3)) * 128;
    int n0 = (local >> 2) * 128;                  // 56 n-panels
    f32x4 acc[4][4] = {};
    mgemm_core(xb, Wt, 1024, m0, n0, As, Bs, acc);
    int lane = threadIdx.x & 63, wave = threadIdx.x >> 6;
    int wr = wave >> 1, wc = wave & 1;
    int rng = n0 >> 10;           // 0,1:pt1  2:wg  3:mag  4:q1  5,6:mix
    float gt = gtemp[0];
    #pragma unroll
    for (int i = 0; i < 4; i++) {
        int mb = m0 + wr*64 + i*16 + (lane>>4)*4;
        #pragma unroll
        for (int j = 0; j < 4; j++) {
            int n = n0 + wc*64 + j*16 + (lane&15);
            #pragma unroll
            for (int r = 0; r < 4; r++) {
                int m = mb + r;
                float v = acc[i][j][r];
                if (rng < 2) {
                    H1b[(size_t)m*D2 + n] = f2bf(geluf(v + b_pt1[n]));
                } else if (rng == 2) {
                    wgb[(size_t)m*DD + n-2048] = f2bf(sigmf((v + b_wg[n-2048])*gt));
                } else if (rng == 3) {
                    magb[(size_t)m*DD + n-3072] = f2bf(sigmf(v + b_mag[n-3072])*5.0f);
                } else if (rng == 4) {
                    Hqb[(size_t)m*DD + n-4096] = f2bf(geluf(v + b_q1[n-4096]));
                } else {
                    mixb[(size_t)m*D2 + n-5120] = f2bf(sigmf(v + b_mix[n-5120]));
                }
            }
        }
    }
}

// z=0: pd = (H1 @ w_pt2 + b_pt2) * |iscale| (K=2048);  z=1: qadj = Hq @ w_q2 + b_q2 (K=1024)
__global__ __launch_bounds__(256,4) void mgemmBC_k(
    const ushort* __restrict__ H1b, const ushort* __restrict__ wt_pt2,
    const ushort* __restrict__ Hqb, const ushort* __restrict__ wt_q2,
    const float* __restrict__ b_pt2, const float* __restrict__ b_q2,
    const float* __restrict__ iscale,
    float* __restrict__ pd, float* __restrict__ qadj)
{
    __shared__ ushort As[2][4096], Bs[2][4096];
    int bid = blockIdx.x;
    int xcd = bid & 7, local = bid >> 3;          // [0,64)
    int m0 = (xcd*4 + (local & 3)) * 128;
    int rest = local >> 2;                        // [0,16)
    int z = rest >> 3;
    int n0 = (rest & 7) * 128;
    const ushort* A  = z ? Hqb   : H1b;
    const ushort* Bt = z ? wt_q2 : wt_pt2;
    const float* bias = z ? b_q2 : b_pt2;
    int K = z ? 1024 : 2048;
    float* outp = z ? qadj : pd;
    f32x4 acc[4][4] = {};
    mgemm_core(A, Bt, K, m0, n0, As, Bs, acc);
    int lane = threadIdx.x & 63, wave = threadIdx.x >> 6;
    int wr = wave >> 1, wc = wave & 1;
    #pragma unroll
    for (int i = 0; i < 4; i++) {
        int mb = m0 + wr*64 + i*16 + (lane>>4)*4;
        #pragma unroll
        for (int j = 0; j < 4; j++) {
            int n = n0 + wc*64 + j*16 + (lane&15);
            float bv = bias[n];
            float sc = z ? 1.0f : fabsf(iscale[n]);
            #pragma unroll
            for (int r = 0; r < 4; r++) {
                float v = acc[i][j][r] + bv;
                outp[(size_t)(mb+r)*DD + n] = z ? v : v*sc;
            }
        }
    }
}

// head GEMMs; 1D grid 256
template<int ACT, bool RESID, bool OUTBF16>
__global__ __launch_bounds__(256,4) void mgemm_k(
    const ushort* __restrict__ A, const ushort* __restrict__ Bt,
    const float* __restrict__ bias, const float* __restrict__ resid,
    void* __restrict__ Cout, int N, int K)
{
    __shared__ ushort As[2][4096], Bs[2][4096];
    int bid = blockIdx.x;
    int xcd = bid & 7, local = bid >> 3;          // [0,32)
    int m0 = (xcd*4 + (local & 3)) * 128;
    int n0 = (local >> 2) * 128;                  // 8 n-panels
    f32x4 acc[4][4] = {};
    mgemm_core(A, Bt, K, m0, n0, As, Bs, acc);
    int lane = threadIdx.x & 63, wave = threadIdx.x >> 6;
    int wr = wave >> 1, wc = wave & 1;
    #pragma unroll
    for (int i = 0; i < 4; i++) {
        int mb = m0 + wr*64 + i*16 + (lane>>4)*4;
        #pragma unroll
        for (int j = 0; j < 4; j++) {
            int n = n0 + wc*64 + j*16 + (lane&15);
            float bv = bias[n];
            #pragma unroll
            for (int r = 0; r < 4; r++) {
                size_t idx = (size_t)(mb + r)*N + n;
                float v = acc[i][j][r] + bv;
                if (ACT==1) v = geluf(v);
                if (RESID) v += resid[idx];
                if (OUTBF16) ((ushort*)Cout)[idx] = f2bf(v);
                else         ((float*)Cout)[idx]  = v;
            }
        }
    }
}

// ---------------- conversions ----------------
__global__ __launch_bounds__(256) void cvt_bf16_k(const float* __restrict__ in, ushort* __restrict__ outp){
    size_t i = ((size_t)blockIdx.x*256 + threadIdx.x)*8;
    float4 a = *(const float4*)(in + i);
    float4 b = *(const float4*)(in + i + 4);
    ushort t[8];
    t[0]=f2bf(a.x); t[1]=f2bf(a.y); t[2]=f2bf(a.z); t[3]=f2bf(a.w);
    t[4]=f2bf(b.x); t[5]=f2bf(b.y); t[6]=f2bf(b.z); t[7]=f2bf(b.w);
    *(int4*)(outp + i) = *(const int4*)t;
}

__device__ __forceinline__ void tcvt_body(const float* W, ushort* Wt, int K, int N){
    __shared__ float tile[32][33];
    int n0 = blockIdx.x*32, k0 = blockIdx.y*32;
    int tx = threadIdx.x & 7, ty = threadIdx.x >> 3;
    float4 v = *(const float4*)(W + (size_t)(k0+ty)*N + n0 + tx*4);
    tile[ty][tx*4+0]=v.x; tile[ty][tx*4+1]=v.y; tile[ty][tx*4+2]=v.z; tile[ty][tx*4+3]=v.w;
    __syncthreads();
    ushort t[4];
    #pragma unroll
    for (int i=0;i<4;i++) t[i] = f2bf(tile[tx*4+i][ty]);
    *(uint2*)(Wt + (size_t)(n0+ty)*K + k0 + tx*4) = *(const uint2*)t;
}

__global__ __launch_bounds__(256) void tcvt_k(const float* __restrict__ W, ushort* __restrict__ Wt, int K, int N){
    tcvt_body(W, Wt, K, N);
}
__global__ __launch_bounds__(256) void tcvt2_k(const float* __restrict__ w0, ushort* __restrict__ o0,
                                               const float* __restrict__ w1, ushort* __restrict__ o1){
    tcvt_body(blockIdx.z ? w1 : w0, blockIdx.z ? o1 : o0, 1024, 2048);
}
__global__ __launch_bounds__(256) void tcvt6_k(
    const float* __restrict__ w0, ushort* __restrict__ o0,
    const float* __restrict__ w1, ushort* __restrict__ o1,
    const float* __restrict__ w2, ushort* __restrict__ o2,
    const float* __restrict__ w3, ushort* __restrict__ o3,
    const float* __restrict__ w4, ushort* __restrict__ o4,
    const float* __restrict__ w5, ushort* __restrict__ o5)
{
    const float* W; ushort* Wt;
    switch(blockIdx.z){
        case 0: W=w0; Wt=o0; break;
        case 1: W=w1; Wt=o1; break;
        case 2: W=w2; Wt=o2; break;
        case 3: W=w3; Wt=o3; break;
        case 4: W=w4; Wt=o4; break;
        default: W=w5; Wt=o5; break;
    }
    tcvt_body(W, Wt, 1024, 1024);
}

// ---------------- scan complex (recompute-on-the-fly) ----------------
__global__ __launch_bounds__(256) void passA_k(
    const float* __restrict__ pd, float* __restrict__ csum)
{
    int d = blockIdx.x*256 + threadIdx.x;
    int c = blockIdx.y, b = blockIdx.z;
    const float* p = pd + ((size_t)b*SS + (size_t)c*CL2)*DD + d;
    float s = 0.f;
    for (int i = 0; i < CL2; i++) s += p[(size_t)i*DD];
    csum[((size_t)b*NC2 + c)*DD + d] = s;
}

__global__ void scan2_k(float* __restrict__ csum, int nchains){
    int idx = blockIdx.x*256 + threadIdx.x;
    if (idx >= nchains) return;
    int xg = idx / DD, d = idx % DD;
    float* p = csum + (size_t)xg*NC2*DD + d;
    float run = 0.f;
    for (int c = 0; c < NC2; c++){ float t = p[(size_t)c*DD]; p[(size_t)c*DD] = run; run += t; }
}

__global__ __launch_bounds__(256) void passB_k(
    const float* __restrict__ pd, const ushort* __restrict__ wgb,
    const ushort* __restrict__ magb, const float* __restrict__ x,
    const float* __restrict__ csum_phi, float* __restrict__ csum_tri)
{
    int d = blockIdx.x*256 + threadIdx.x;
    int c = blockIdx.y, b = blockIdx.z;
    size_t off = ((size_t)b*SS + (size_t)c*CL2)*DD + d;
    float ph = csum_phi[((size_t)b*NC2 + c)*DD + d];
    float s0=0.f, s1=0.f, s2=0.f;
    for (int i = 0; i < CL2; i++){
        size_t o = off + (size_t)i*DD;
        ph += pd[o];
        float w = bf2f(wgb[o]), m = bf2f(magb[o]);
        float ct = w*x[o]*m;
        float sp, cp; sincosf(ph, &sp, &cp);
        s0 += ct*cp; s1 += ct*sp; s2 += fmaf(w, m, 1e-8f);
    }
    size_t cs = ((size_t)b*NC2 + c)*DD + d;
    size_t G = (size_t)BB*NC2*DD;
    csum_tri[cs]=s0; csum_tri[G+cs]=s1; csum_tri[2*G+cs]=s2;
}

__global__ __launch_bounds__(256) void passC_k(
    const float* __restrict__ pd, const ushort* __restrict__ wgb,
    const ushort* __restrict__ magb, const float* __restrict__ x,
    const float* __restrict__ qadj, const ushort* __restrict__ mixb,
    const float* __restrict__ csum_phi, const float* __restrict__ csum_tri,
    ushort* __restrict__ ret)
{
    int d = blockIdx.x*256 + threadIdx.x;
    int c = blockIdx.y, b = blockIdx.z;
    size_t off = ((size_t)b*SS + (size_t)c*CL2)*DD + d;
    size_t cs = ((size_t)b*NC2 + c)*DD + d;
    size_t G = (size_t)BB*NC2*DD;
    float ph = csum_phi[cs];
    float r0 = csum_tri[cs], r1 = csum_tri[G+cs], r2 = csum_tri[2*G+cs];
    size_t row0 = (size_t)b*SS + (size_t)c*CL2;
    for (int i = 0; i < CL2; i++){
        size_t o = off + (size_t)i*DD;
        ph += pd[o];
        float w = bf2f(wgb[o]), m = bf2f(magb[o]);
        float ct = w*x[o]*m;
        float sp, cp; sincosf(ph, &sp, &cp);
        r0 += ct*cp; r1 += ct*sp; r2 += fmaf(w, m, 1e-8f);
        float inv = rsqrtf(r2);
        float mr = r0*inv, mi = r1*inv;
        float q = ph + qadj[o];
        float sq, cq; sincosf(q, &sq, &cq);
        float rr = mr*cq + mi*sq;
        float ri = mi*cq - mr*sq;
        size_t mb2 = (row0 + i)*D2 + d;
        ret[o] = f2bf(bf2f(mixb[mb2])*rr + bf2f(mixb[mb2+DD])*ri);
    }
}

// LayerNorm over d per row; bf16 in/out
__global__ __launch_bounds__(256) void ln_k(
    const ushort* __restrict__ ret, const float* __restrict__ ln_g,
    const float* __restrict__ ln_b, ushort* __restrict__ outp)
{
    int row = blockIdx.x;
    size_t base = (size_t)row*DD;
    float vals[4];
    float sum=0.f, sumsq=0.f;
    #pragma unroll
    for (int k = 0; k < 4; k++){
        int d = threadIdx.x + k*256;
        float v = bf2f(ret[base+d]);
        vals[k]=v; sum+=v; sumsq = fmaf(v,v,sumsq);
    }
    #pragma unroll
    for (int off=32; off; off>>=1){
        sum   += __shfl_down(sum,off);
        sumsq += __shfl_down(sumsq,off);
    }
    __shared__ float red[8];
    int lane = threadIdx.x & 63, wid = threadIdx.x >> 6;
    if (lane==0){ red[wid]=sum; red[4+wid]=sumsq; }
    __syncthreads();
    sum   = red[0]+red[1]+red[2]+red[3];
    sumsq = red[4]+red[5]+red[6]+red[7];
    float mu  = sum * (1.0f/DD);
    float var = sumsq*(1.0f/DD) - mu*mu;
    float rstd = rsqrtf(var + 1e-5f);
    #pragma unroll
    for (int k = 0; k < 4; k++){
        int d = threadIdx.x + k*256;
        outp[base+d] = f2bf((vals[k]-mu)*rstd*ln_g[d] + ln_b[d]);
    }
}

extern "C" void kernel_launch(void* const* d_in, const int* in_sizes, int n_in,
                              void* d_out, int out_size, void* d_ws, size_t ws_size,
                              hipStream_t stream)
{
    const float* x     = (const float*)d_in[0];
    const float* w_pt1 = (const float*)d_in[1];
    const float* b_pt1 = (const float*)d_in[2];
    const float* w_pt2 = (const float*)d_in[3];
    const float* b_pt2 = (const float*)d_in[4];
    const float* iscale= (const float*)d_in[5];
    const float* w_wg  = (const float*)d_in[6];
    const float* b_wg  = (const float*)d_in[7];
    const float* gtemp = (const float*)d_in[8];
    const float* w_mag = (const float*)d_in[9];
    const float* b_mag = (const float*)d_in[10];
    const float* w_q1  = (const float*)d_in[11];
    const float* b_q1  = (const float*)d_in[12];
    const float* w_q2  = (const float*)d_in[13];
    const float* b_q2  = (const float*)d_in[14];
    const float* w_mix = (const float*)d_in[15];
    const float* b_mix = (const float*)d_in[16];
    const float* ln_g  = (const float*)d_in[17];
    const float* ln_b  = (const float*)d_in[18];
    const float* w_o1  = (const float*)d_in[19];
    const float* b_o1  = (const float*)d_in[20];
    const float* w_o2  = (const float*)d_in[21];
    const float* b_o2  = (const float*)d_in[22];
    float* out = (float*)d_out;

    const size_t SZ = (size_t)MTOT*DD;     // 4M elems
    ushort* u = (ushort*)d_ws;
    ushort* xb    = u;                 u += SZ;        // bf16 x
    ushort* H1b   = u;                 u += 2*SZ;      // [4096][2048]
    ushort* ret   = H1b;                                // alias (H1b dead after BC)
    ushort* Hqb   = u;                 u += SZ;
    ushort* lnb   = Hqb;                                // alias (Hqb dead after BC)
    ushort* wgb   = u;                 u += SZ;
    ushort* magb  = u;                 u += SZ;
    ushort* mixb  = u;                 u += 2*SZ;      // [4096][2048]
    ushort* Hob   = u;                 u += SZ;
    float*  pd    = (float*)u;         u += 2*SZ;      // fp32
    float*  qadj  = (float*)u;         u += 2*SZ;      // fp32
    ushort* Wt_all= u;                 u += (size_t)7168*1024;
    ushort* wt_pt2= u;                 u += (size_t)1024*2048;
    ushort* wt_q2 = u;                 u += (size_t)1024*1024;
    ushort* wt_o1 = u;                 u += (size_t)1024*1024;
    ushort* wt_o2 = u;                 u += (size_t)1024*1024;
    float* csum_phi = (float*)u;                       // BB*NC2*DD
    float* csum_tri = csum_phi + (size_t)BB*NC2*DD;    // 3x

    dim3 blk(256);
    // conversions
    cvt_bf16_k<<<dim3(SZ/2048), blk, 0, stream>>>(x, xb);
    tcvt2_k<<<dim3(64, 32, 2), blk, 0, stream>>>(w_pt1, Wt_all, w_mix, Wt_all + (size_t)5120*1024);
    tcvt6_k<<<dim3(32, 32, 6), blk, 0, stream>>>(
        w_wg,  Wt_all + (size_t)2048*1024,
        w_mag, Wt_all + (size_t)3072*1024,
        w_q1,  Wt_all + (size_t)4096*1024,
        w_q2,  wt_q2,  w_o1, wt_o1,  w_o2, wt_o2);
    tcvt_k<<<dim3(32, 64), blk, 0, stream>>>(w_pt2, wt_pt2, 2048, 1024);
    // fused GEMM A (1792 blocks, XCD-chunked)
    mgemmA_k<<<dim3(1792), blk, 0, stream>>>(xb, Wt_all, b_pt1, b_wg, b_mag, b_q1, b_mix,
                                             gtemp, H1b, wgb, magb, Hqb, mixb);
    // GEMM B/C (512 blocks)
    mgemmBC_k<<<dim3(512), blk, 0, stream>>>(H1b, wt_pt2, Hqb, wt_q2, b_pt2, b_q2,
                                             iscale, pd, qadj);
    // scan complex
    passA_k<<<dim3(DD/256, NC2, BB), blk, 0, stream>>>(pd, csum_phi);
    scan2_k<<<dim3((BB*DD+255)/256), blk, 0, stream>>>(csum_phi, BB*DD);
    passB_k<<<dim3(DD/256, NC2, BB), blk, 0, stream>>>(pd, wgb, magb, x, csum_phi, csum_tri);
    scan2_k<<<dim3((3*BB*DD+255)/256), blk, 0, stream>>>(csum_tri, 3*BB*DD);
    passC_k<<<dim3(DD/256, NC2, BB), blk, 0, stream>>>(pd, wgb, magb, x, qadj, mixb,
                                                       csum_phi, csum_tri, ret);
    ln_k<<<dim3(MTOT), blk, 0, stream>>>(ret, ln_g, ln_b, lnb);
    // output head (256 blocks each)
    mgemm_k<1,false,true><<<dim3(256), blk, 0, stream>>>(lnb, wt_o1, b_o1, nullptr, Hob, DD, DD);
    mgemm_k<0,true,false><<<dim3(256), blk, 0, stream>>>(Hob, wt_o2, b_o2, x, out, DD, DD);
}

// Round 6
// 267.240 us; speedup vs baseline: 1.4189x; 1.0530x over previous
//
#include <hip/hip_runtime.h>
#include <hip/hip_bf16.h>

#define MTOT 4096   // B*S
#define DD   1024
#define D2   2048
#define SS   2048
#define BB   2
#define NC2  64
#define CL2  (SS/NC2)   // 32

typedef __attribute__((ext_vector_type(8))) short bf16x8;
typedef __attribute__((ext_vector_type(4))) float f32x4;

__device__ __forceinline__ float sigmf(float v){
    return 1.0f/(1.0f+__expf(-v));
}
__device__ __forceinline__ float geluf(float v){
    float u = 0.7978845608f*v*(1.0f + 0.044715f*v*v);
    float e = __expf(2.0f*u);
    float t = 1.0f - 2.0f/(e + 1.0f);
    return 0.5f*v*(1.0f + t);
}
__device__ __forceinline__ ushort f2bf(float f){
    unsigned u = __float_as_uint(f);
    unsigned r = (u + 0x7FFF + ((u>>16)&1)) >> 16;
    return (ushort)r;
}
__device__ __forceinline__ float bf2f(ushort u){
    return __uint_as_float(((unsigned)u)<<16);
}

// ---------------- bf16 MFMA GEMM core ----------------
// 128x128 tile, 4 waves (64x64 each, 4x4 frags of 16x16x32), BK=32.
// LDS tile [128][32] bf16 (64B rows). Bank fix: 16B slot s is stored at
// physical slot s^((row>>1)&3)  (rows already toggle bank-bit4 via row bit0,
// so the swizzle uses row bits 1-2). Applied as: linear global_load_lds dest
// + inverse-swizzled GLOBAL source column + swizzled ds_read (rule #21).
__device__ __forceinline__ void stage_tile(
    const ushort* __restrict__ A, const ushort* __restrict__ Bt, int K,
    int m0, int n0, int k0, ushort* As, ushort* Bs)
{
    int tid = threadIdx.x;
    #pragma unroll
    for (int i = 0; i < 2; i++) {
        int e = (i*256 + tid) * 8;          // elem in [128][32] tile (linear LDS)
        int r = e >> 5;
        int s = (e >> 3) & 3;
        int c = ((s ^ ((r >> 1) & 3)) << 3);   // inverse-swizzled source col
        __builtin_amdgcn_global_load_lds(
            (const __attribute__((address_space(1))) void*)(A + (size_t)(m0 + r)*K + k0 + c),
            (__attribute__((address_space(3))) void*)(As + e), 16, 0, 0);
        __builtin_amdgcn_global_load_lds(
            (const __attribute__((address_space(1))) void*)(Bt + (size_t)(n0 + r)*K + k0 + c),
            (__attribute__((address_space(3))) void*)(Bs + e), 16, 0, 0);
    }
}

__device__ __forceinline__ void load_frags(
    const ushort* As, const ushort* Bs, int wr, int wc, int lrow, int cs,
    bf16x8 (&af)[4], bf16x8 (&bfr)[4])
{
    #pragma unroll
    for (int i = 0; i < 4; i++) {
        int ra = wr*64 + i*16 + lrow;
        int rb = wc*64 + i*16 + lrow;
        af[i]  = *(const bf16x8*)(As + ra*32 + ((cs ^ ((ra>>1)&3))<<3));
        bfr[i] = *(const bf16x8*)(Bs + rb*32 + ((cs ^ ((rb>>1)&3))<<3));
    }
}

__device__ __forceinline__ void do_mfma(
    const bf16x8 (&af)[4], const bf16x8 (&bfr)[4], f32x4 (&acc)[4][4])
{
    __builtin_amdgcn_s_setprio(1);
    #pragma unroll
    for (int i = 0; i < 4; i++)
        #pragma unroll
        for (int j = 0; j < 4; j++)
            acc[i][j] = __builtin_amdgcn_mfma_f32_16x16x32_bf16(af[i], bfr[j], acc[i][j], 0, 0, 0);
    __builtin_amdgcn_s_setprio(0);
}

// Depth-2 counted-vmcnt pipeline (T3+T4): vmcnt never drains to 0 in the
// steady-state loop; stage of tile t+2 is issued before the MFMA cluster of
// tile t and has ~2 compute phases to land.
__device__ __forceinline__ void mgemm_core(
    const ushort* __restrict__ A, const ushort* __restrict__ Bt, int K,
    int m0, int n0, ushort (&As)[2][4096], ushort (&Bs)[2][4096], f32x4 (&acc)[4][4])
{
    int lane = threadIdx.x & 63, wave = threadIdx.x >> 6;
    int wr = wave >> 1, wc = wave & 1;
    int lrow = lane & 15, cs = lane >> 4;
    int NT = K >> 5;
    stage_tile(A, Bt, K, m0, n0, 0,  As[0], Bs[0]);   // 4 loads/thread
    stage_tile(A, Bt, K, m0, n0, 32, As[1], Bs[1]);   // 4 more (8 outstanding)
    for (int t = 0; t < NT-1; ++t) {
        // tile t's 4 loads retired; t+1's 4 stay in flight across the barrier
        asm volatile("s_waitcnt vmcnt(4)" ::: "memory");
        __builtin_amdgcn_s_barrier();
        bf16x8 af[4], bfr[4];
        load_frags(As[t&1], Bs[t&1], wr, wc, lrow, cs, af, bfr);
        if (t < NT-2) {
            // all waves done reading buf[t&1] -> safe to overwrite with t+2
            asm volatile("s_waitcnt lgkmcnt(0)" ::: "memory");
            __builtin_amdgcn_s_barrier();
            stage_tile(A, Bt, K, m0, n0, (t+2) << 5, As[t&1], Bs[t&1]);
        }
        __builtin_amdgcn_sched_barrier(0);   // keep MFMAs after the stage issue
        do_mfma(af, bfr, acc);
    }
    // final tile: drain
    asm volatile("s_waitcnt vmcnt(0)" ::: "memory");
    __builtin_amdgcn_s_barrier();
    bf16x8 af[4], bfr[4];
    load_frags(As[(NT-1)&1], Bs[(NT-1)&1], wr, wc, lrow, cs, af, bfr);
    do_mfma(af, bfr, acc);
}

// Fused GEMM A: xb @ [w_pt1 | w_wg | w_mag | w_q1 | w_mix], N=7168, K=1024.
__global__ __launch_bounds__(256,4) void mgemmA_k(
    const ushort* __restrict__ xb, const ushort* __restrict__ Wt,
    const float* __restrict__ b_pt1, const float* __restrict__ b_wg,
    const float* __restrict__ b_mag, const float* __restrict__ b_q1,
    const float* __restrict__ b_mix, const float* __restrict__ gtemp,
    ushort* __restrict__ H1b, ushort* __restrict__ wgb, ushort* __restrict__ magb,
    ushort* __restrict__ Hqb, ushort* __restrict__ mixb)
{
    __shared__ ushort As[2][4096], Bs[2][4096];
    int bid = blockIdx.x;
    int xcd = bid & 7, local = bid >> 3;          // local in [0,224)
    int m0 = (xcd*4 + (local & 3)) * 128;
    int n0 = (local >> 2) * 128;                  // 56 n-panels
    f32x4 acc[4][4] = {};
    mgemm_core(xb, Wt, 1024, m0, n0, As, Bs, acc);
    int lane = threadIdx.x & 63, wave = threadIdx.x >> 6;
    int wr = wave >> 1, wc = wave & 1;
    int rng = n0 >> 10;           // 0,1:pt1  2:wg  3:mag  4:q1  5,6:mix
    float gt = gtemp[0];
    #pragma unroll
    for (int i = 0; i < 4; i++) {
        int mb = m0 + wr*64 + i*16 + (lane>>4)*4;
        #pragma unroll
        for (int j = 0; j < 4; j++) {
            int n = n0 + wc*64 + j*16 + (lane&15);
            #pragma unroll
            for (int r = 0; r < 4; r++) {
                int m = mb + r;
                float v = acc[i][j][r];
                if (rng < 2) {
                    H1b[(size_t)m*D2 + n] = f2bf(geluf(v + b_pt1[n]));
                } else if (rng == 2) {
                    wgb[(size_t)m*DD + n-2048] = f2bf(sigmf((v + b_wg[n-2048])*gt));
                } else if (rng == 3) {
                    magb[(size_t)m*DD + n-3072] = f2bf(sigmf(v + b_mag[n-3072])*5.0f);
                } else if (rng == 4) {
                    Hqb[(size_t)m*DD + n-4096] = f2bf(geluf(v + b_q1[n-4096]));
                } else {
                    mixb[(size_t)m*D2 + n-5120] = f2bf(sigmf(v + b_mix[n-5120]));
                }
            }
        }
    }
}

// z=0: pd = (H1 @ w_pt2 + b_pt2) * |iscale| (K=2048);  z=1: qadj = Hq @ w_q2 + b_q2 (K=1024)
__global__ __launch_bounds__(256,4) void mgemmBC_k(
    const ushort* __restrict__ H1b, const ushort* __restrict__ wt_pt2,
    const ushort* __restrict__ Hqb, const ushort* __restrict__ wt_q2,
    const float* __restrict__ b_pt2, const float* __restrict__ b_q2,
    const float* __restrict__ iscale,
    float* __restrict__ pd, float* __restrict__ qadj)
{
    __shared__ ushort As[2][4096], Bs[2][4096];
    int bid = blockIdx.x;
    int xcd = bid & 7, local = bid >> 3;          // [0,64)
    int m0 = (xcd*4 + (local & 3)) * 128;
    int rest = local >> 2;                        // [0,16)
    int z = rest >> 3;
    int n0 = (rest & 7) * 128;
    const ushort* A  = z ? Hqb   : H1b;
    const ushort* Bt = z ? wt_q2 : wt_pt2;
    const float* bias = z ? b_q2 : b_pt2;
    int K = z ? 1024 : 2048;
    float* outp = z ? qadj : pd;
    f32x4 acc[4][4] = {};
    mgemm_core(A, Bt, K, m0, n0, As, Bs, acc);
    int lane = threadIdx.x & 63, wave = threadIdx.x >> 6;
    int wr = wave >> 1, wc = wave & 1;
    #pragma unroll
    for (int i = 0; i < 4; i++) {
        int mb = m0 + wr*64 + i*16 + (lane>>4)*4;
        #pragma unroll
        for (int j = 0; j < 4; j++) {
            int n = n0 + wc*64 + j*16 + (lane&15);
            float bv = bias[n];
            float sc = z ? 1.0f : fabsf(iscale[n]);
            #pragma unroll
            for (int r = 0; r < 4; r++) {
                float v = acc[i][j][r] + bv;
                outp[(size_t)(mb+r)*DD + n] = z ? v : v*sc;
            }
        }
    }
}

// head GEMMs; 1D grid 256
template<int ACT, bool RESID, bool OUTBF16>
__global__ __launch_bounds__(256,4) void mgemm_k(
    const ushort* __restrict__ A, const ushort* __restrict__ Bt,
    const float* __restrict__ bias, const float* __restrict__ resid,
    void* __restrict__ Cout, int N, int K)
{
    __shared__ ushort As[2][4096], Bs[2][4096];
    int bid = blockIdx.x;
    int xcd = bid & 7, local = bid >> 3;          // [0,32)
    int m0 = (xcd*4 + (local & 3)) * 128;
    int n0 = (local >> 2) * 128;                  // 8 n-panels
    f32x4 acc[4][4] = {};
    mgemm_core(A, Bt, K, m0, n0, As, Bs, acc);
    int lane = threadIdx.x & 63, wave = threadIdx.x >> 6;
    int wr = wave >> 1, wc = wave & 1;
    #pragma unroll
    for (int i = 0; i < 4; i++) {
        int mb = m0 + wr*64 + i*16 + (lane>>4)*4;
        #pragma unroll
        for (int j = 0; j < 4; j++) {
            int n = n0 + wc*64 + j*16 + (lane&15);
            float bv = bias[n];
            #pragma unroll
            for (int r = 0; r < 4; r++) {
                size_t idx = (size_t)(mb + r)*N + n;
                float v = acc[i][j][r] + bv;
                if (ACT==1) v = geluf(v);
                if (RESID) v += resid[idx];
                if (OUTBF16) ((ushort*)Cout)[idx] = f2bf(v);
                else         ((float*)Cout)[idx]  = v;
            }
        }
    }
}

// ---------------- conversions ----------------
__global__ __launch_bounds__(256) void cvt_bf16_k(const float* __restrict__ in, ushort* __restrict__ outp){
    size_t i = ((size_t)blockIdx.x*256 + threadIdx.x)*8;
    float4 a = *(const float4*)(in + i);
    float4 b = *(const float4*)(in + i + 4);
    ushort t[8];
    t[0]=f2bf(a.x); t[1]=f2bf(a.y); t[2]=f2bf(a.z); t[3]=f2bf(a.w);
    t[4]=f2bf(b.x); t[5]=f2bf(b.y); t[6]=f2bf(b.z); t[7]=f2bf(b.w);
    *(int4*)(outp + i) = *(const int4*)t;
}

__device__ __forceinline__ void tcvt_body(const float* W, ushort* Wt, int K, int N){
    __shared__ float tile[32][33];
    int n0 = blockIdx.x*32, k0 = blockIdx.y*32;
    int tx = threadIdx.x & 7, ty = threadIdx.x >> 3;
    float4 v = *(const float4*)(W + (size_t)(k0+ty)*N + n0 + tx*4);
    tile[ty][tx*4+0]=v.x; tile[ty][tx*4+1]=v.y; tile[ty][tx*4+2]=v.z; tile[ty][tx*4+3]=v.w;
    __syncthreads();
    ushort t[4];
    #pragma unroll
    for (int i=0;i<4;i++) t[i] = f2bf(tile[tx*4+i][ty]);
    *(uint2*)(Wt + (size_t)(n0+ty)*K + k0 + tx*4) = *(const uint2*)t;
}

__global__ __launch_bounds__(256) void tcvt_k(const float* __restrict__ W, ushort* __restrict__ Wt, int K, int N){
    tcvt_body(W, Wt, K, N);
}
__global__ __launch_bounds__(256) void tcvt2_k(const float* __restrict__ w0, ushort* __restrict__ o0,
                                               const float* __restrict__ w1, ushort* __restrict__ o1){
    tcvt_body(blockIdx.z ? w1 : w0, blockIdx.z ? o1 : o0, 1024, 2048);
}
__global__ __launch_bounds__(256) void tcvt6_k(
    const float* __restrict__ w0, ushort* __restrict__ o0,
    const float* __restrict__ w1, ushort* __restrict__ o1,
    const float* __restrict__ w2, ushort* __restrict__ o2,
    const float* __restrict__ w3, ushort* __restrict__ o3,
    const float* __restrict__ w4, ushort* __restrict__ o4,
    const float* __restrict__ w5, ushort* __restrict__ o5)
{
    const float* W; ushort* Wt;
    switch(blockIdx.z){
        case 0: W=w0; Wt=o0; break;
        case 1: W=w1; Wt=o1; break;
        case 2: W=w2; Wt=o2; break;
        case 3: W=w3; Wt=o3; break;
        case 4: W=w4; Wt=o4; break;
        default: W=w5; Wt=o5; break;
    }
    tcvt_body(W, Wt, 1024, 1024);
}

// ---------------- scan complex (recompute-on-the-fly) ----------------
__global__ __launch_bounds__(256) void passA_k(
    const float* __restrict__ pd, float* __restrict__ csum)
{
    int d = blockIdx.x*256 + threadIdx.x;
    int c = blockIdx.y, b = blockIdx.z;
    const float* p = pd + ((size_t)b*SS + (size_t)c*CL2)*DD + d;
    float s = 0.f;
    for (int i = 0; i < CL2; i++) s += p[(size_t)i*DD];
    csum[((size_t)b*NC2 + c)*DD + d] = s;
}

__global__ void scan2_k(float* __restrict__ csum, int nchains){
    int idx = blockIdx.x*256 + threadIdx.x;
    if (idx >= nchains) return;
    int xg = idx / DD, d = idx % DD;
    float* p = csum + (size_t)xg*NC2*DD + d;
    float run = 0.f;
    for (int c = 0; c < NC2; c++){ float t = p[(size_t)c*DD]; p[(size_t)c*DD] = run; run += t; }
}

__global__ __launch_bounds__(256) void passB_k(
    const float* __restrict__ pd, const ushort* __restrict__ wgb,
    const ushort* __restrict__ magb, const ushort* __restrict__ xb,
    const float* __restrict__ csum_phi, float* __restrict__ csum_tri)
{
    int d = blockIdx.x*256 + threadIdx.x;
    int c = blockIdx.y, b = blockIdx.z;
    size_t off = ((size_t)b*SS + (size_t)c*CL2)*DD + d;
    float ph = csum_phi[((size_t)b*NC2 + c)*DD + d];
    float s0=0.f, s1=0.f, s2=0.f;
    for (int i = 0; i < CL2; i++){
        size_t o = off + (size_t)i*DD;
        ph += pd[o];
        float w = bf2f(wgb[o]), m = bf2f(magb[o]);
        float ct = w*bf2f(xb[o])*m;
        float sp, cp; sincosf(ph, &sp, &cp);
        s0 += ct*cp; s1 += ct*sp; s2 += fmaf(w, m, 1e-8f);
    }
    size_t cs = ((size_t)b*NC2 + c)*DD + d;
    size_t G = (size_t)BB*NC2*DD;
    csum_tri[cs]=s0; csum_tri[G+cs]=s1; csum_tri[2*G+cs]=s2;
}

__global__ __launch_bounds__(256) void passC_k(
    const float* __restrict__ pd, const ushort* __restrict__ wgb,
    const ushort* __restrict__ magb, const ushort* __restrict__ xb,
    const float* __restrict__ qadj, const ushort* __restrict__ mixb,
    const float* __restrict__ csum_phi, const float* __restrict__ csum_tri,
    ushort* __restrict__ ret)
{
    int d = blockIdx.x*256 + threadIdx.x;
    int c = blockIdx.y, b = blockIdx.z;
    size_t off = ((size_t)b*SS + (size_t)c*CL2)*DD + d;
    size_t cs = ((size_t)b*NC2 + c)*DD + d;
    size_t G = (size_t)BB*NC2*DD;
    float ph = csum_phi[cs];
    float r0 = csum_tri[cs], r1 = csum_tri[G+cs], r2 = csum_tri[2*G+cs];
    size_t row0 = (size_t)b*SS + (size_t)c*CL2;
    for (int i = 0; i < CL2; i++){
        size_t o = off + (size_t)i*DD;
        ph += pd[o];
        float w = bf2f(wgb[o]), m = bf2f(magb[o]);
        float ct = w*bf2f(xb[o])*m;
        float sp, cp; sincosf(ph, &sp, &cp);
        r0 += ct*cp; r1 += ct*sp; r2 += fmaf(w, m, 1e-8f);
        float inv = rsqrtf(r2);
        float mr = r0*inv, mi = r1*inv;
        float q = ph + qadj[o];
        float sq, cq; sincosf(q, &sq, &cq);
        float rr = mr*cq + mi*sq;
        float ri = mi*cq - mr*sq;
        size_t mb2 = (row0 + i)*D2 + d;
        ret[o] = f2bf(bf2f(mixb[mb2])*rr + bf2f(mixb[mb2+DD])*ri);
    }
}

// LayerNorm over d per row; bf16 in/out
__global__ __launch_bounds__(256) void ln_k(
    const ushort* __restrict__ ret, const float* __restrict__ ln_g,
    const float* __restrict__ ln_b, ushort* __restrict__ outp)
{
    int row = blockIdx.x;
    size_t base = (size_t)row*DD;
    float vals[4];
    float sum=0.f, sumsq=0.f;
    #pragma unroll
    for (int k = 0; k < 4; k++){
        int d = threadIdx.x + k*256;
        float v = bf2f(ret[base+d]);
        vals[k]=v; sum+=v; sumsq = fmaf(v,v,sumsq);
    }
    #pragma unroll
    for (int off=32; off; off>>=1){
        sum   += __shfl_down(sum,off);
        sumsq += __shfl_down(sumsq,off);
    }
    __shared__ float red[8];
    int lane = threadIdx.x & 63, wid = threadIdx.x >> 6;
    if (lane==0){ red[wid]=sum; red[4+wid]=sumsq; }
    __syncthreads();
    sum   = red[0]+red[1]+red[2]+red[3];
    sumsq = red[4]+red[5]+red[6]+red[7];
    float mu  = sum * (1.0f/DD);
    float var = sumsq*(1.0f/DD) - mu*mu;
    float rstd = rsqrtf(var + 1e-5f);
    #pragma unroll
    for (int k = 0; k < 4; k++){
        int d = threadIdx.x + k*256;
        outp[base+d] = f2bf((vals[k]-mu)*rstd*ln_g[d] + ln_b[d]);
    }
}

extern "C" void kernel_launch(void* const* d_in, const int* in_sizes, int n_in,
                              void* d_out, int out_size, void* d_ws, size_t ws_size,
                              hipStream_t stream)
{
    const float* x     = (const float*)d_in[0];
    const float* w_pt1 = (const float*)d_in[1];
    const float* b_pt1 = (const float*)d_in[2];
    const float* w_pt2 = (const float*)d_in[3];
    const float* b_pt2 = (const float*)d_in[4];
    const float* iscale= (const float*)d_in[5];
    const float* w_wg  = (const float*)d_in[6];
    const float* b_wg  = (const float*)d_in[7];
    const float* gtemp = (const float*)d_in[8];
    const float* w_mag = (const float*)d_in[9];
    const float* b_mag = (const float*)d_in[10];
    const float* w_q1  = (const float*)d_in[11];
    const float* b_q1  = (const float*)d_in[12];
    const float* w_q2  = (const float*)d_in[13];
    const float* b_q2  = (const float*)d_in[14];
    const float* w_mix = (const float*)d_in[15];
    const float* b_mix = (const float*)d_in[16];
    const float* ln_g  = (const float*)d_in[17];
    const float* ln_b  = (const float*)d_in[18];
    const float* w_o1  = (const float*)d_in[19];
    const float* b_o1  = (const float*)d_in[20];
    const float* w_o2  = (const float*)d_in[21];
    const float* b_o2  = (const float*)d_in[22];
    float* out = (float*)d_out;

    const size_t SZ = (size_t)MTOT*DD;     // 4M elems
    ushort* u = (ushort*)d_ws;
    ushort* xb    = u;                 u += SZ;        // bf16 x
    ushort* H1b   = u;                 u += 2*SZ;      // [4096][2048]
    ushort* ret   = H1b;                                // alias (H1b dead after BC)
    ushort* Hqb   = u;                 u += SZ;
    ushort* lnb   = Hqb;                                // alias (Hqb dead after BC)
    ushort* wgb   = u;                 u += SZ;
    ushort* magb  = u;                 u += SZ;
    ushort* mixb  = u;                 u += 2*SZ;      // [4096][2048]
    ushort* Hob   = u;                 u += SZ;
    float*  pd    = (float*)u;         u += 2*SZ;      // fp32
    float*  qadj  = (float*)u;         u += 2*SZ;      // fp32
    ushort* Wt_all= u;                 u += (size_t)7168*1024;
    ushort* wt_pt2= u;                 u += (size_t)1024*2048;
    ushort* wt_q2 = u;                 u += (size_t)1024*1024;
    ushort* wt_o1 = u;                 u += (size_t)1024*1024;
    ushort* wt_o2 = u;                 u += (size_t)1024*1024;
    float* csum_phi = (float*)u;                       // BB*NC2*DD
    float* csum_tri = csum_phi + (size_t)BB*NC2*DD;    // 3x

    dim3 blk(256);
    // conversions
    cvt_bf16_k<<<dim3(SZ/2048), blk, 0, stream>>>(x, xb);
    tcvt2_k<<<dim3(64, 32, 2), blk, 0, stream>>>(w_pt1, Wt_all, w_mix, Wt_all + (size_t)5120*1024);
    tcvt6_k<<<dim3(32, 32, 6), blk, 0, stream>>>(
        w_wg,  Wt_all + (size_t)2048*1024,
        w_mag, Wt_all + (size_t)3072*1024,
        w_q1,  Wt_all + (size_t)4096*1024,
        w_q2,  wt_q2,  w_o1, wt_o1,  w_o2, wt_o2);
    tcvt_k<<<dim3(32, 64), blk, 0, stream>>>(w_pt2, wt_pt2, 2048, 1024);
    // fused GEMM A (1792 blocks, XCD-chunked)
    mgemmA_k<<<dim3(1792), blk, 0, stream>>>(xb, Wt_all, b_pt1, b_wg, b_mag, b_q1, b_mix,
                                             gtemp, H1b, wgb, magb, Hqb, mixb);
    // GEMM B/C (512 blocks)
    mgemmBC_k<<<dim3(512), blk, 0, stream>>>(H1b, wt_pt2, Hqb, wt_q2, b_pt2, b_q2,
                                             iscale, pd, qadj);
    // scan complex
    passA_k<<<dim3(DD/256, NC2, BB), blk, 0, stream>>>(pd, csum_phi);
    scan2_k<<<dim3((BB*DD+255)/256), blk, 0, stream>>>(csum_phi, BB*DD);
    passB_k<<<dim3(DD/256, NC2, BB), blk, 0, stream>>>(pd, wgb, magb, xb, csum_phi, csum_tri);
    scan2_k<<<dim3((3*BB*DD+255)/256), blk, 0, stream>>>(csum_tri, 3*BB*DD);
    passC_k<<<dim3(DD/256, NC2, BB), blk, 0, stream>>>(pd, wgb, magb, xb, qadj, mixb,
                                                       csum_phi, csum_tri, ret);
    ln_k<<<dim3(MTOT), blk, 0, stream>>>(ret, ln_g, ln_b, lnb);
    // output head (256 blocks each)
    mgemm_k<1,false,true><<<dim3(256), blk, 0, stream>>>(lnb, wt_o1, b_o1, nullptr, Hob, DD, DD);
    mgemm_k<0,true,false><<<dim3(256), blk, 0, stream>>>(Hob, wt_o2, b_o2, x, out, DD, DD);
}